// Round 5
// baseline (508.313 us; speedup 1.0000x reference)
//
#include <hip/hip_runtime.h>
#include <hip/hip_cooperative_groups.h>
#include <math.h>
#include <stddef.h>

namespace cg = cooperative_groups;

// ---------- problem constants ----------
#define B_   8
#define A_   64
#define L_   256
#define P_   20
#define SD_  8
#define MF_  6
#define H_   256
#define NH_  8
#define HD_  32
#define NL_  3
#define C_   64
#define S_   30
#define N_   321          // 1 + A_ + L_
#define NTOK (B_*N_)      // 2568

__device__ inline float waveSum(float v){
#pragma unroll
  for(int o=32;o;o>>=1) v += __shfl_down(v,o,64);
  return v;
}

struct Params {
  const float *ego, *agents, *mp;
  const float *w_ego, *b_ego, *w_ag, *b_ag, *w_map, *b_map, *ln_g, *ln_b;
  const float *attn_in_w, *attn_in_b, *attn_out_w, *attn_out_b;
  const float *mlp_w1, *mlp_b1, *mlp_w2, *mlp_b2, *pl_g, *pl_b;
  const float *traj_w, *traj_b, *score_w, *score_b;
  float *tokens, *K, *V, *wqT, *wkT, *wvT, *aowT;
  float *fusedv, *yv, *h1v, *attv, *ldir, *validv;
  float *o_traj, *o_logits, *o_scores, *o_selidx, *o_seltraj;
  float *o_mind, *o_laned, *o_align, *o_cost;
  unsigned *bar;
};

// 8-block (one batch) device-scope barrier. Counter zeroed per launch.
__device__ inline void batchBarrier(unsigned* cnt){
  __syncthreads();                      // all stores of this block retired (vmcnt drained)
  if(threadIdx.x==0){
    __threadfence();                    // release: make stores device-visible
    atomicAdd(cnt, 1u);
    while(atomicAdd(cnt, 0u) < 8u){}
    __threadfence();                    // acquire: invalidate caches before release
  }
  __syncthreads();
}

// =====================================================================
// MEGA cooperative kernel: entire graph in one launch.
// =====================================================================
__global__ void __launch_bounds__(256,2) mega(Params p){
  cg::grid_group grid = cg::this_grid();
  const int blk = blockIdx.x, t = threadIdx.x;
  const int nb = gridDim.x;
  __shared__ __align__(16) float pool[64*65];   // 16.6 KB, aliased per stage
  __shared__ float red[8];
  __shared__ int bad;

  // ---------------- stage 1: encode tokens + weight transposes + ldir ----
  for(int u = blk; u < NTOK+64+8; u += nb){
    if(u < NTOK){
      int b = u / N_, n = u % N_;
      float* in_s = pool;       // 8
      float* arr  = pool + 16;  // 120
      const float* W; const float* bias; int D;
      if(n==0){
        if(t<SD_) in_s[t] = p.ego[(b*10+9)*SD_+t];
        W=p.w_ego; bias=p.b_ego; D=SD_;
      } else if(n<=A_){
        int a=n-1;
        if(t<SD_) in_s[t] = p.agents[(size_t)(b*A_+a)*SD_+t];
        W=p.w_ag; bias=p.b_ag; D=SD_;
      } else {
        int l=n-1-A_;
        if(t<120) arr[t] = p.mp[(size_t)(b*L_+l)*120 + t];
        __syncthreads();
        if(t<MF_){
          float s=0.f;
#pragma unroll
          for(int q=0;q<P_;q++) s += arr[q*MF_+t];
          in_s[t] = s*(1.0f/P_);
        }
        W=p.w_map; bias=p.b_map; D=MF_;
      }
      __syncthreads();
      float acc = bias[t];
      for(int d=0;d<D;d++) acc += in_s[d]*W[d*H_+t];
      float s1=acc, s2=acc*acc;
#pragma unroll
      for(int o=32;o;o>>=1){ s1+=__shfl_down(s1,o,64); s2+=__shfl_down(s2,o,64); }
      if((t&63)==0){ red[t>>6]=s1; red[4+(t>>6)]=s2; }
      __syncthreads();
      float m = (red[0]+red[1]+red[2]+red[3])*(1.0f/H_);
      float v = (red[4]+red[5]+red[6]+red[7])*(1.0f/H_) - m*m;
      p.tokens[(size_t)u*H_+t] = (acc-m)*rsqrtf(v+1e-5f)*p.ln_g[t] + p.ln_b[t];
      __syncthreads();
    } else if(u < NTOK+64){
      int tid2 = u - NTOK;
      int mat = tid2 >> 4, tile = tid2 & 15;
      int jt = (tile>>2)*64, dt = (tile&3)*64;
      const float* src; float* dst;
      if(mat==0){ src = p.attn_in_w;            dst = p.wqT; }
      else if(mat==1){ src = p.attn_in_w + 256*H_; dst = p.wkT; }
      else if(mat==2){ src = p.attn_in_w + 512*H_; dst = p.wvT; }
      else { src = p.attn_out_w; dst = p.aowT; }
      int c = t & 63, r0 = (t>>6)*16;
      float* tile_s = pool;   // [64][65]
#pragma unroll
      for(int r=0;r<16;r++) tile_s[(r0+r)*65+c] = src[(size_t)(jt+r0+r)*H_ + dt + c];
      __syncthreads();
#pragma unroll
      for(int r=0;r<16;r++) dst[(size_t)(dt+r0+r)*H_ + jt + c] = tile_s[c*65 + r0+r];
      __syncthreads();
    } else {
      int b = u - (NTOK+64);
      const float* p0 = p.mp + (size_t)(b*L_ + t)*120;
      float dx = p0[19*MF_+0]-p0[0];
      float dy = p0[19*MF_+1]-p0[1];
#pragma unroll
      for(int o=32;o;o>>=1){ dx+=__shfl_down(dx,o,64); dy+=__shfl_down(dy,o,64); }
      if((t&63)==0){ red[t>>6]=dx; red[4+(t>>6)]=dy; }
      __syncthreads();
      if(t==0){
        float sx = (red[0]+red[1]+red[2]+red[3])*(1.0f/L_);
        float sy = (red[4]+red[5]+red[6]+red[7])*(1.0f/L_);
        float nm = fmaxf(sqrtf(sx*sx+sy*sy), 1e-6f);
        p.ldir[b*2]=sx/nm; p.ldir[b*2+1]=sy/nm;
      }
      __syncthreads();
    }
  }
  grid.sync();

  // ---------------- stage 2: K/V projection (8 tokens / unit) ------------
  for(int u = blk; u < NTOK/8; u += nb){
    int base = u*8;
    float* tok = pool;   // [8][256]
#pragma unroll
    for(int k=0;k<8;k++) tok[k*H_+t] = p.tokens[(size_t)(base+k)*H_+t];
    __syncthreads();
    float bk = p.attn_in_b[256+t], bv = p.attn_in_b[512+t];
    float aK[8], aV[8];
#pragma unroll
    for(int k=0;k<8;k++){ aK[k]=bk; aV[k]=bv; }
#pragma unroll 4
    for(int d=0;d<H_;d++){
      float wk = p.wkT[d*H_+t], wv = p.wvT[d*H_+t];
#pragma unroll
      for(int k=0;k<8;k++){ float x=tok[k*H_+d]; aK[k]+=x*wk; aV[k]+=x*wv; }
    }
#pragma unroll
    for(int k=0;k<8;k++){
      p.K[(size_t)(base+k)*H_+t]=aK[k];
      p.V[(size_t)(base+k)*H_+t]=aV[k];
    }
    __syncthreads();
  }
  grid.sync();

  // ---------------- stage 3: 3-layer fusion on blocks 0..63 --------------
  // b = blk&7 so one batch's 8 blocks share an XCD (round-robin mapping).
  if(blk < 64){
    const int b = blk & 7, h = blk >> 3;
    float* x_s   = pool;         // 256
    float* q_s   = pool + 256;   // 32 (16B aligned)
    float* att_s = pool + 288;   // 321 -> ends 609
    float* part1 = pool + 640;   // 256
    float* part2 = pool + 896;   // 256 -> 1152
    float* xa_s  = pool;         // phase-B aliases
    float* xh_s  = pool + 256;   // 512
    float* partB = pool + 768;   // 32*9

    for(int layer=0; layer<NL_; ++layer){
      // ---- phase A: LN -> x_s ----
      if(layer==0){
        x_s[t] = p.tokens[((size_t)b*N_)*H_ + t];
      } else {
        float yvv = p.yv[b*H_+t];
        float s1=yvv, s2=yvv*yvv;
#pragma unroll
        for(int o=32;o;o>>=1){ s1+=__shfl_down(s1,o,64); s2+=__shfl_down(s2,o,64); }
        if((t&63)==0){ red[t>>6]=s1; red[4+(t>>6)]=s2; }
        __syncthreads();
        float m = (red[0]+red[1]+red[2]+red[3])*(1.0f/H_);
        float v = (red[4]+red[5]+red[6]+red[7])*(1.0f/H_) - m*m;
        x_s[t] = (yvv-m)*rsqrtf(v+1e-5f)*p.pl_g[t] + p.pl_b[t];
      }
      __syncthreads();
      if(h==0) p.fusedv[b*H_+t] = x_s[t];
      // Q slice (head h, 32 cols, 8-way K-split)
      {
        int c=t&31, ks=t>>5;
        const float* w = p.wqT + (size_t)(ks*32)*H_ + h*HD_ + c;
        float a=0.f;
#pragma unroll 8
        for(int d=0;d<32;d++) a += x_s[ks*32+d]*w[(size_t)d*H_];
        part1[t]=a;
      }
      // MLP1 slice (64 cols, 4-way K-split)
      {
        int c2=t&63, k2=t>>6;
        const float* w1 = p.mlp_w1 + (size_t)layer*H_*512 + (size_t)(k2*64)*512 + h*64 + c2;
        float a=0.f;
#pragma unroll 8
        for(int d=0;d<64;d++) a += x_s[k2*64+d]*w1[(size_t)d*512];
        part2[t]=a;
      }
      __syncthreads();
      if(t<32){
        float q = p.attn_in_b[h*HD_+t];
#pragma unroll
        for(int ks=0;ks<8;ks++) q += part1[ks*32+t];
        q_s[t]=q;
      }
      if(t<64){
        float v = p.mlp_b1[layer*512 + h*64 + t];
#pragma unroll
        for(int k2=0;k2<4;k2++) v += part2[k2*64+t];
        p.h1v[b*512 + h*64 + t] = v*0.5f*(1.0f+erff(v*0.70710678118654752f));
      }
      __syncthreads();
      // ---- scores ----
      float4 q4[8];
      {
        const float4* qp=(const float4*)q_s;
#pragma unroll
        for(int i=0;i<8;i++) q4[i]=qp[i];
      }
      float s0;
      {
        const float4* kp=(const float4*)(p.K + ((size_t)(b*N_+t))*H_ + h*HD_);
        float s=0.f;
#pragma unroll
        for(int i=0;i<8;i++){ float4 kk=kp[i]; s+=kk.x*q4[i].x+kk.y*q4[i].y+kk.z*q4[i].z+kk.w*q4[i].w; }
        s0 = s*0.17677669529663687f;
      }
      float s1v = -3.0e38f;
      if(t<65){
        const float4* kp=(const float4*)(p.K + ((size_t)(b*N_+256+t))*H_ + h*HD_);
        float s=0.f;
#pragma unroll
        for(int i=0;i<8;i++){ float4 kk=kp[i]; s+=kk.x*q4[i].x+kk.y*q4[i].y+kk.z*q4[i].z+kk.w*q4[i].w; }
        s1v = s*0.17677669529663687f;
      }
      float mx = fmaxf(s0, s1v);
#pragma unroll
      for(int o=32;o;o>>=1) mx = fmaxf(mx, __shfl_xor(mx,o,64));
      if((t&63)==0) red[t>>6]=mx;
      __syncthreads();
      mx = fmaxf(fmaxf(red[0],red[1]),fmaxf(red[2],red[3]));
      __syncthreads();
      float p0 = expf(s0-mx);
      att_s[t]=p0;
      float lsum=p0;
      if(t<65){ float p1=expf(s1v-mx); att_s[256+t]=p1; lsum+=p1; }
#pragma unroll
      for(int o=32;o;o>>=1) lsum += __shfl_xor(lsum,o,64);
      if((t&63)==0) red[4+(t>>6)]=lsum;
      __syncthreads();
      // ---- AV ----
      {
        int o=t&31, ks=t>>5;
        int n0=ks*40, n1=(ks==7)?N_:n0+40;
        const float* Vp = p.V + ((size_t)(b*N_))*H_ + h*HD_ + o;
        float a=0.f;
        for(int n=n0;n<n1;n++) a += att_s[n]*Vp[(size_t)n*H_];
        part1[t]=a;
      }
      __syncthreads();
      if(t<32){
        float inv = 1.0f/(red[4]+red[5]+red[6]+red[7]);
        float a=0.f;
#pragma unroll
        for(int ks=0;ks<8;ks++) a += part1[ks*32+t];
        p.attv[b*H_ + h*HD_ + t] = a*inv;
      }
      batchBarrier(p.bar + b*6 + layer*2);
      // ---- phase B: out-proj + MLP2 + residual (32 cols/block) ----
      xa_s[t] = p.attv[b*H_+t];
      xh_s[t] = p.h1v[b*512+t];
      xh_s[256+t] = p.h1v[b*512+256+t];
      __syncthreads();
      {
        int c=t&31, rs=t>>5;       // 8 row-slices of 96
        int col = h*32 + c;
        float a=0.f;
        int r0=rs*96, r1=r0+96;
        int rEndA = r1<256 ? r1 : 256;
        for(int r=r0; r<rEndA; ++r) a += xa_s[r]*p.aowT[(size_t)r*H_+col];
        const float* w2 = p.mlp_w2 + (size_t)layer*512*H_;
        int rBegB = r0>256 ? r0 : 256;
        for(int r=rBegB; r<r1; ++r){ int rr=r-256; a += xh_s[rr]*w2[(size_t)rr*H_+col]; }
        partB[c*9+rs]=a;
      }
      __syncthreads();
      if(t<32){
        float s=0.f;
#pragma unroll
        for(int k=0;k<8;k++) s += partB[t*9+k];
        int colo = h*32+t;
        p.yv[b*H_+colo] = s + p.attn_out_b[colo] + p.mlp_b2[layer*H_+colo] + p.fusedv[b*H_+colo];
      }
      batchBarrier(p.bar + b*6 + layer*2 + 1);
    }
  }
  grid.sync();

  // ---------------- stage 4: final LN + decode + constraints -------------
  for(int u = blk; u < B_*C_; u += nb){
    int b = u>>6, c = u&63;
    int j = t&63, sl = t>>6;
    float* fs  = pool;        // 256
    float* pt4 = pool+256;    // 4*64
    float* ds  = pool+512;    // 60
    float* ts  = pool+576;    // 60
    float* as_ = pool+640;    // 128
    float* redsc = pool+770;  // 4
    float yvv = p.yv[b*H_+t];
    float s1=yvv, s2=yvv*yvv;
#pragma unroll
    for(int o=32;o;o>>=1){ s1+=__shfl_down(s1,o,64); s2+=__shfl_down(s2,o,64); }
    if((t&63)==0){ red[t>>6]=s1; red[4+(t>>6)]=s2; }
    if(t==0) bad=0;
    __syncthreads();
    {
      float m = (red[0]+red[1]+red[2]+red[3])*(1.0f/H_);
      float v = (red[4]+red[5]+red[6]+red[7])*(1.0f/H_) - m*m;
      fs[t] = (yvv-m)*rsqrtf(v+1e-5f)*p.pl_g[t] + p.pl_b[t];
    }
    __syncthreads();
    if(j < 60){
      int col = c*60 + j;
      const float* w = p.traj_w + (size_t)(sl*64)*3840 + col;
      float acc=0.f;
#pragma unroll 16
      for(int d=0;d<64;d++) acc += fs[sl*64+d]*w[(size_t)d*3840];
      pt4[sl*64+j] = acc;
    }
    float lp = fs[t]*p.score_w[t*64 + c];
    lp = waveSum(lp);
    if((t&63)==0) redsc[t>>6]=lp;
    if(t>=128 && t<256){ int q=t-128; as_[q] = p.agents[(size_t)(b*A_ + (q>>1))*SD_ + (q&1)]; }
    __syncthreads();
    if(t < 60){
      float a = pt4[t]+pt4[64+t]+pt4[128+t]+pt4[192+t] + p.traj_b[c*60+t];
      ds[t] = tanhf(a)*1.5f;   // MAX_STEP
    }
    if(t==0) p.o_logits[b*64+c] = redsc[0]+redsc[1]+redsc[2]+redsc[3] + p.score_b[c];
    __syncthreads();
    if(t<2){
      float x = p.ego[(b*10+9)*SD_ + t];
      for(int s=0;s<S_;s++){ x += ds[s*2+t]; ts[s*2+t] = x; }
    }
    __syncthreads();
    if(t<60) p.o_traj[(size_t)(b*64+c)*60 + t] = ts[t];
    if(t<29){
      float dx = ts[2*t+2]-ts[2*t], dy = ts[2*t+3]-ts[2*t+1];
      if((dx*dx+dy*dy)*100.0f > 225.0f) bad=1;
    }
    if(t<28){
      float x0=ts[2*t],y0=ts[2*t+1],x1=ts[2*t+2],y1=ts[2*t+3],x2=ts[2*t+4],y2=ts[2*t+5];
      float ddx = x2-2.f*x1+x0, ddy = y2-2.f*y1+y0;
      if((ddx*ddx+ddy*ddy)*10000.0f > 25.0f) bad=1;
      float d1x=x1-x0, d1y=y1-y0;
      float cross = d1x*ddy - d1y*ddx;
      float n2 = d1x*d1x+d1y*d1y;
      float n3 = fmaxf(n2*sqrtf(n2), 1e-6f);
      if(fabsf(cross) > 0.3f*n3) bad=1;
    }
    float md2 = 3.0e38f;
    for(int idx=t; idx<S_*A_; idx+=256){
      int s = idx>>6, a = idx&63;
      float dx = ts[2*s]-as_[2*a], dy = ts[2*s+1]-as_[2*a+1];
      md2 = fminf(md2, dx*dx+dy*dy);
    }
    float lx[20], ly[20];
#pragma unroll
    for(int k=0;k<20;k++){
      int i = t + k*256;
      const float* pp = p.mp + (size_t)(b*5120 + i)*MF_;
      lx[k]=pp[0]; ly[k]=pp[1];
    }
    float ld2 = 3.0e38f;
    for(int s=0;s<S_;s++){
      float tx=ts[2*s], ty=ts[2*s+1];
#pragma unroll
      for(int k=0;k<20;k++){
        float dx=tx-lx[k], dy=ty-ly[k];
        ld2 = fminf(ld2, dx*dx+dy*dy);
      }
    }
    __syncthreads();
#pragma unroll
    for(int o=32;o;o>>=1) md2 = fminf(md2, __shfl_down(md2,o,64));
    if((t&63)==0) red[t>>6]=md2;
    __syncthreads();
    md2 = fminf(fminf(red[0],red[1]),fminf(red[2],red[3]));
    __syncthreads();
#pragma unroll
    for(int o=32;o;o>>=1) ld2 = fminf(ld2, __shfl_down(ld2,o,64));
    if((t&63)==0) red[t>>6]=ld2;
    __syncthreads();
    ld2 = fminf(fminf(red[0],red[1]),fminf(red[2],red[3]));
    __syncthreads();
    if(t==0){
      float md = sqrtf(md2), ld = sqrtf(ld2);
      float tdx = ts[58]-ts[0], tdy = ts[59]-ts[1];
      float nm = fmaxf(sqrtf(tdx*tdx+tdy*tdy), 1e-6f);
      tdx/=nm; tdy/=nm;
      float al = tdx*p.ldir[b*2] + tdy*p.ldir[b*2+1];
      int ok = (!bad) && (md>=1.5f) && (ld<=4.5f) && (al>=0.0f);
      int oi = b*64+c;
      p.o_mind[oi]=md; p.o_laned[oi]=ld; p.o_align[oi]=al;
      p.o_cost[oi] = fmaxf(1.5f-md,0.0f) + 0.1f*ld + 0.5f*fmaxf(1.0f-al,0.0f);
      p.validv[oi] = ok ? 1.0f : 0.0f;
    }
    __syncthreads();
  }
  grid.sync();

  // ---------------- stage 5: score softmax + selection -------------------
  if(blk < 8 && t < 64){
    int b = blk;
    float lg = p.o_logits[b*64+t];
    float mx = lg;
#pragma unroll
    for(int o=32;o;o>>=1) mx = fmaxf(mx, __shfl_xor(mx,o,64));
    float e = expf(lg-mx);
    float sm = e;
#pragma unroll
    for(int o=32;o;o>>=1) sm += __shfl_xor(sm,o,64);
    float sc = e/sm;
    p.o_scores[b*64+t] = sc;
    bool v = p.validv[b*64+t] > 0.5f;
    unsigned long long bal = __ballot(v);
    float sv = v ? sc : -1.0f;
    float v1=sv; int i1=t;
    float v2=sc; int i2=t;
#pragma unroll
    for(int o=32;o;o>>=1){
      float ov=__shfl_down(v1,o,64); int oi=__shfl_down(i1,o,64);
      if(ov>v1 || (ov==v1 && oi<i1)){ v1=ov; i1=oi; }
      ov=__shfl_down(v2,o,64); oi=__shfl_down(i2,o,64);
      if(ov>v2 || (ov==v2 && oi<i2)){ v2=ov; i2=oi; }
    }
    int sel = (bal!=0ULL) ? i1 : i2;
    sel = __shfl(sel, 0, 64);
    if(t==0) p.o_selidx[b] = (float)sel;
    if(t<60) p.o_seltraj[b*60+t] = p.o_traj[(size_t)(b*64+sel)*60 + t];
  }
}

// =====================================================================
// Fallback path: round-4 multi-kernel pipeline (used only if the
// cooperative launch is rejected).
// =====================================================================
__global__ void __launch_bounds__(256) k_prep_encode(
    const float* __restrict__ ego, const float* __restrict__ agents,
    const float* __restrict__ mp,
    const float* __restrict__ w_ego, const float* __restrict__ b_ego,
    const float* __restrict__ w_ag,  const float* __restrict__ b_ag,
    const float* __restrict__ w_map, const float* __restrict__ b_map,
    const float* __restrict__ ln_g,  const float* __restrict__ ln_b,
    const float* __restrict__ attn_in_w, const float* __restrict__ attn_out_w,
    float* __restrict__ tokens,
    float* __restrict__ wqT, float* __restrict__ wkT,
    float* __restrict__ wvT, float* __restrict__ aowT,
    float* __restrict__ ldir){
  int blk = blockIdx.x;
  int j = threadIdx.x;
  __shared__ float tile_s[64][65];
  __shared__ float in_s[SD_];
  __shared__ float arr[120];
  __shared__ float red[8];
  if(blk < NTOK){
    int b = blk / N_;
    int n = blk % N_;
    const float* W; const float* bias; int D;
    if(n==0){
      if(j<SD_) in_s[j] = ego[(b*10 + 9)*SD_ + j];
      W=w_ego; bias=b_ego; D=SD_;
    } else if(n<=A_){
      int a=n-1;
      if(j<SD_) in_s[j] = agents[(size_t)(b*A_+a)*SD_ + j];
      W=w_ag; bias=b_ag; D=SD_;
    } else {
      int l=n-1-A_;
      if(j<120) arr[j] = mp[(size_t)(b*L_+l)*120 + j];
      __syncthreads();
      if(j<MF_){
        float s=0.f;
#pragma unroll
        for(int pq=0;pq<P_;pq++) s += arr[pq*MF_+j];
        in_s[j] = s * (1.0f/P_);
      }
      W=w_map; bias=b_map; D=MF_;
    }
    __syncthreads();
    float acc = bias[j];
    for(int d=0;d<D;d++) acc += in_s[d]*W[d*H_ + j];
    float s1=acc, s2=acc*acc;
#pragma unroll
    for(int o=32;o;o>>=1){ s1+=__shfl_down(s1,o,64); s2+=__shfl_down(s2,o,64); }
    if((j&63)==0){ red[j>>6]=s1; red[4+(j>>6)]=s2; }
    __syncthreads();
    float m = (red[0]+red[1]+red[2]+red[3]) * (1.0f/H_);
    float v = (red[4]+red[5]+red[6]+red[7]) * (1.0f/H_) - m*m;
    tokens[(size_t)blk*H_ + j] = (acc-m)*rsqrtf(v+1e-5f)*ln_g[j] + ln_b[j];
  } else if(blk < NTOK+64){
    int tid2 = blk - NTOK;
    int mat = tid2 >> 4;
    int tile = tid2 & 15;
    int jt = (tile>>2)*64, dt = (tile&3)*64;
    const float* src; float* dst;
    if(mat==0){ src = attn_in_w;            dst = wqT; }
    else if(mat==1){ src = attn_in_w + 256*H_; dst = wkT; }
    else if(mat==2){ src = attn_in_w + 512*H_; dst = wvT; }
    else { src = attn_out_w; dst = aowT; }
    int c = j & 63, r0 = (j>>6)*16;
#pragma unroll
    for(int r=0;r<16;r++) tile_s[r0+r][c] = src[(size_t)(jt + r0 + r)*H_ + dt + c];
    __syncthreads();
#pragma unroll
    for(int r=0;r<16;r++) dst[(size_t)(dt + r0 + r)*H_ + jt + c] = tile_s[c][r0+r];
  } else {
    int b = blk - (NTOK+64);
    const float* p0 = mp + (size_t)(b*L_ + j)*120;
    float dx = p0[19*MF_+0]-p0[0];
    float dy = p0[19*MF_+1]-p0[1];
#pragma unroll
    for(int o=32;o;o>>=1){ dx+=__shfl_down(dx,o,64); dy+=__shfl_down(dy,o,64); }
    if((j&63)==0){ red[j>>6]=dx; red[4+(j>>6)]=dy; }
    __syncthreads();
    if(j==0){
      float sx = (red[0]+red[1]+red[2]+red[3])*(1.0f/L_);
      float sy = (red[4]+red[5]+red[6]+red[7])*(1.0f/L_);
      float nm = fmaxf(sqrtf(sx*sx+sy*sy), 1e-6f);
      ldir[b*2]=sx/nm; ldir[b*2+1]=sy/nm;
    }
  }
}

__global__ void __launch_bounds__(256) k_kv(
    const float* __restrict__ tokens,
    const float* __restrict__ wkT, const float* __restrict__ wvT,
    const float* __restrict__ attn_in_b,
    float* __restrict__ K, float* __restrict__ V){
  int base = blockIdx.x * 8;
  int j = threadIdx.x;
  __shared__ float tok_s[8][H_];
#pragma unroll
  for(int t=0;t<8;t++) tok_s[t][j] = tokens[(size_t)(base+t)*H_ + j];
  __syncthreads();
  float bk = attn_in_b[256+j], bv = attn_in_b[512+j];
  float aK[8], aV[8];
#pragma unroll
  for(int t=0;t<8;t++){ aK[t]=bk; aV[t]=bv; }
#pragma unroll 4
  for(int d=0;d<H_;d++){
    float wk = wkT[d*H_+j], wv = wvT[d*H_+j];
#pragma unroll
    for(int t=0;t<8;t++){ float x=tok_s[t][d]; aK[t]+=x*wk; aV[t]+=x*wv; }
  }
#pragma unroll
  for(int t=0;t<8;t++){
    K[(size_t)(base+t)*H_+j]=aK[t];
    V[(size_t)(base+t)*H_+j]=aV[t];
  }
}

__global__ void __launch_bounds__(256) k_attn_mlp1(
    const float* __restrict__ tokens, const float* __restrict__ y,
    const float* __restrict__ K, const float* __restrict__ V,
    const float* __restrict__ wqT, const float* __restrict__ attn_in_b,
    const float* __restrict__ mlp_w1, const float* __restrict__ mlp_b1,
    const float* __restrict__ pl_g, const float* __restrict__ pl_b,
    float* __restrict__ fusedv, float* __restrict__ h1v,
    float* __restrict__ attv, int layer){
  int b = blockIdx.x >> 3;
  int h = blockIdx.x & 7;
  int t = threadIdx.x;
  __shared__ __align__(16) float x_s[H_];
  __shared__ __align__(16) float q_s[HD_];
  __shared__ float att_s[N_+7];
  __shared__ float part1[8*32];
  __shared__ float part2[4*64];
  __shared__ float red[8];
  if(layer==0){
    x_s[t] = tokens[((size_t)b*N_)*H_ + t];
  } else {
    float yv = y[b*H_ + t];
    float s1=yv, s2=yv*yv;
#pragma unroll
    for(int o=32;o;o>>=1){ s1+=__shfl_down(s1,o,64); s2+=__shfl_down(s2,o,64); }
    if((t&63)==0){ red[t>>6]=s1; red[4+(t>>6)]=s2; }
    __syncthreads();
    float m = (red[0]+red[1]+red[2]+red[3])*(1.0f/H_);
    float v = (red[4]+red[5]+red[6]+red[7])*(1.0f/H_) - m*m;
    x_s[t] = (yv-m)*rsqrtf(v+1e-5f)*pl_g[t] + pl_b[t];
  }
  __syncthreads();
  if(h==0) fusedv[b*H_ + t] = x_s[t];
  {
    int c = t & 31, ks = t >> 5;
    const float* w = wqT + (size_t)(ks*32)*H_ + h*HD_ + c;
    float acc = 0.f;
#pragma unroll 8
    for(int d=0;d<32;d++) acc += x_s[ks*32+d] * w[(size_t)d*H_];
    part1[t] = acc;
  }
  {
    int c2 = t & 63, k2 = t >> 6;
    const float* w1 = mlp_w1 + (size_t)layer*H_*512 + (size_t)(k2*64)*512 + h*64 + c2;
    float acc2 = 0.f;
#pragma unroll 8
    for(int d=0;d<64;d++) acc2 += x_s[k2*64+d] * w1[(size_t)d*512];
    part2[t] = acc2;
  }
  __syncthreads();
  if(t < 32){
    float q = attn_in_b[h*HD_ + t];
#pragma unroll
    for(int ks=0;ks<8;ks++) q += part1[ks*32+t];
    q_s[t] = q;
  }
  if(t < 64){
    float v = mlp_b1[layer*512 + h*64 + t];
#pragma unroll
    for(int k2=0;k2<4;k2++) v += part2[k2*64+t];
    h1v[b*512 + h*64 + t] = v*0.5f*(1.0f+erff(v*0.70710678118654752f));
  }
  __syncthreads();
  float4 q4[8];
  {
    const float4* qp = (const float4*)q_s;
#pragma unroll
    for(int i=0;i<8;i++) q4[i] = qp[i];
  }
  float s0;
  {
    const float4* kp = (const float4*)(K + ((size_t)(b*N_+t))*H_ + h*HD_);
    float s=0.f;
#pragma unroll
    for(int i=0;i<8;i++){ float4 kk=kp[i]; s += kk.x*q4[i].x + kk.y*q4[i].y + kk.z*q4[i].z + kk.w*q4[i].w; }
    s0 = s * 0.17677669529663687f;
  }
  float s1v = -3.0e38f;
  if(t < 65){
    const float4* kp = (const float4*)(K + ((size_t)(b*N_+256+t))*H_ + h*HD_);
    float s=0.f;
#pragma unroll
    for(int i=0;i<8;i++){ float4 kk=kp[i]; s += kk.x*q4[i].x + kk.y*q4[i].y + kk.z*q4[i].z + kk.w*q4[i].w; }
    s1v = s * 0.17677669529663687f;
  }
  float mx = fmaxf(s0, s1v);
#pragma unroll
  for(int o=32;o;o>>=1) mx = fmaxf(mx, __shfl_xor(mx,o,64));
  if((t&63)==0) red[t>>6]=mx;
  __syncthreads();
  mx = fmaxf(fmaxf(red[0],red[1]),fmaxf(red[2],red[3]));
  __syncthreads();
  float p0 = expf(s0-mx);
  att_s[t] = p0;
  float lsum = p0;
  if(t<65){ float p1 = expf(s1v-mx); att_s[256+t] = p1; lsum += p1; }
#pragma unroll
  for(int o=32;o;o>>=1) lsum += __shfl_xor(lsum,o,64);
  if((t&63)==0) red[4+(t>>6)]=lsum;
  __syncthreads();
  float inv = 1.0f/(red[4]+red[5]+red[6]+red[7]);
  {
    int o = t & 31, ks = t >> 5;
    int n0 = ks*40, n1 = (ks==7)? N_ : n0+40;
    const float* Vp = V + ((size_t)(b*N_))*H_ + h*HD_ + o;
    float acc=0.f;
    for(int n=n0;n<n1;n++) acc += att_s[n]*Vp[(size_t)n*H_];
    part1[t] = acc;
  }
  __syncthreads();
  if(t < 32){
    float acc = 0.f;
#pragma unroll
    for(int ks=0;ks<8;ks++) acc += part1[ks*32+t];
    attv[b*H_ + h*HD_ + t] = acc*inv;
  }
}

__global__ void __launch_bounds__(256) k_out_mlp2(
    const float* __restrict__ attv, const float* __restrict__ h1v,
    const float* __restrict__ fusedv,
    const float* __restrict__ aowT, const float* __restrict__ attn_out_b,
    const float* __restrict__ mlp_w2, const float* __restrict__ mlp_b2,
    float* __restrict__ y, int layer){
  int b  = blockIdx.x >> 4;
  int cg_ = blockIdx.x & 15;
  int t = threadIdx.x;
  int c = t & 15, rs = t >> 4;
  int col = cg_*16 + c;
  __shared__ float xa_s[H_];
  __shared__ float xh_s[512];
  __shared__ float part[16][17];
  xa_s[t] = attv[b*H_ + t];
  xh_s[t] = h1v[b*512 + t];
  xh_s[256+t] = h1v[b*512 + 256 + t];
  __syncthreads();
  float acc = 0.f;
  int r0 = rs*48, r1 = r0+48;
  for(int r=r0; r<min(r1,256); ++r) acc += xa_s[r]*aowT[(size_t)r*H_ + col];
  const float* w2 = mlp_w2 + (size_t)layer*512*H_;
  for(int r=max(r0,256); r<r1; ++r){
    int rr = r-256;
    acc += xh_s[rr]*w2[(size_t)rr*H_ + col];
  }
  part[c][rs] = acc;
  __syncthreads();
  if(t < 16){
    int colo = cg_*16 + t;
    float s = 0.f;
#pragma unroll
    for(int k=0;k<16;k++) s += part[t][k];
    y[b*H_ + colo] = s + attn_out_b[colo] + mlp_b2[layer*H_ + colo] + fusedv[b*H_ + colo];
  }
}

__global__ void __launch_bounds__(256) k_decode_constraints(
    const float* __restrict__ y, const float* __restrict__ pl_g,
    const float* __restrict__ pl_b,
    const float* __restrict__ traj_w, const float* __restrict__ traj_b,
    const float* __restrict__ score_w, const float* __restrict__ score_b,
    const float* __restrict__ ego,
    const float* __restrict__ agents, const float* __restrict__ mp,
    const float* __restrict__ ldir,
    float* __restrict__ o_traj, float* __restrict__ o_logits,
    float* __restrict__ o_mind, float* __restrict__ o_laned,
    float* __restrict__ o_align, float* __restrict__ o_cost,
    float* __restrict__ valid){
  int b = blockIdx.x >> 6, c = blockIdx.x & 63;
  int t = threadIdx.x;
  int j = t & 63, sl = t >> 6;
  __shared__ float fs[H_];
  __shared__ float part[4][64];
  __shared__ float ds[60];
  __shared__ float ts[60];
  __shared__ float as_[A_*2];
  __shared__ float red[8];
  __shared__ float redsc[4];
  __shared__ int bad;
  float yv = y[b*H_ + t];
  float s1=yv, s2=yv*yv;
#pragma unroll
  for(int o=32;o;o>>=1){ s1+=__shfl_down(s1,o,64); s2+=__shfl_down(s2,o,64); }
  if((t&63)==0){ red[t>>6]=s1; red[4+(t>>6)]=s2; }
  if(t==0) bad=0;
  __syncthreads();
  {
    float m = (red[0]+red[1]+red[2]+red[3])*(1.0f/H_);
    float v = (red[4]+red[5]+red[6]+red[7])*(1.0f/H_) - m*m;
    fs[t] = (yv-m)*rsqrtf(v+1e-5f)*pl_g[t] + pl_b[t];
  }
  __syncthreads();
  if(j < 60){
    int col = c*60 + j;
    const float* w = traj_w + (size_t)(sl*64)*3840 + col;
    float acc=0.f;
#pragma unroll 16
    for(int d=0;d<64;d++) acc += fs[sl*64+d]*w[(size_t)d*3840];
    part[sl][j] = acc;
  }
  float lp = fs[t]*score_w[t*64 + c];
  lp = waveSum(lp);
  if((t&63)==0) redsc[t>>6]=lp;
  if(t>=128 && t<256){ int q=t-128; as_[q] = agents[(size_t)(b*A_ + (q>>1))*SD_ + (q&1)]; }
  __syncthreads();
  if(t < 60){
    float a = part[0][t]+part[1][t]+part[2][t]+part[3][t] + traj_b[c*60+t];
    ds[t] = tanhf(a)*1.5f;
  }
  if(t==0) o_logits[b*64+c] = redsc[0]+redsc[1]+redsc[2]+redsc[3] + score_b[c];
  __syncthreads();
  if(t<2){
    float x = ego[(b*10+9)*SD_ + t];
    for(int s=0;s<S_;s++){ x += ds[s*2+t]; ts[s*2+t] = x; }
  }
  __syncthreads();
  if(t<60) o_traj[(size_t)(b*64+c)*60 + t] = ts[t];
  if(t<29){
    float dx = ts[2*t+2]-ts[2*t], dy = ts[2*t+3]-ts[2*t+1];
    if((dx*dx+dy*dy)*100.0f > 225.0f) bad=1;
  }
  if(t<28){
    float x0=ts[2*t],y0=ts[2*t+1],x1=ts[2*t+2],y1=ts[2*t+3],x2=ts[2*t+4],y2=ts[2*t+5];
    float ddx = x2-2.f*x1+x0, ddy = y2-2.f*y1+y0;
    if((ddx*ddx+ddy*ddy)*10000.0f > 25.0f) bad=1;
    float d1x=x1-x0, d1y=y1-y0;
    float cross = d1x*ddy - d1y*ddx;
    float n2 = d1x*d1x+d1y*d1y;
    float n3 = fmaxf(n2*sqrtf(n2), 1e-6f);
    if(fabsf(cross) > 0.3f*n3) bad=1;
  }
  float md2 = 3.0e38f;
  for(int idx=t; idx<S_*A_; idx+=256){
    int s = idx>>6, a = idx&63;
    float dx = ts[2*s]-as_[2*a], dy = ts[2*s+1]-as_[2*a+1];
    md2 = fminf(md2, dx*dx+dy*dy);
  }
  float lx[20], ly[20];
#pragma unroll
  for(int k=0;k<20;k++){
    int i = t + k*256;
    const float* pp = mp + (size_t)(b*5120 + i)*MF_;
    lx[k]=pp[0]; ly[k]=pp[1];
  }
  float ld2 = 3.0e38f;
  for(int s=0;s<S_;s++){
    float tx=ts[2*s], ty=ts[2*s+1];
#pragma unroll
    for(int k=0;k<20;k++){
      float dx=tx-lx[k], dy=ty-ly[k];
      ld2 = fminf(ld2, dx*dx+dy*dy);
    }
  }
  __syncthreads();
#pragma unroll
  for(int o=32;o;o>>=1) md2 = fminf(md2, __shfl_down(md2,o,64));
  if((t&63)==0) red[t>>6]=md2;
  __syncthreads();
  md2 = fminf(fminf(red[0],red[1]),fminf(red[2],red[3]));
  __syncthreads();
#pragma unroll
  for(int o=32;o;o>>=1) ld2 = fminf(ld2, __shfl_down(ld2,o,64));
  if((t&63)==0) red[t>>6]=ld2;
  __syncthreads();
  ld2 = fminf(fminf(red[0],red[1]),fminf(red[2],red[3]));
  if(t==0){
    float md = sqrtf(md2), ld = sqrtf(ld2);
    float tdx = ts[58]-ts[0], tdy = ts[59]-ts[1];
    float nm = fmaxf(sqrtf(tdx*tdx+tdy*tdy), 1e-6f);
    tdx/=nm; tdy/=nm;
    float al = tdx*ldir[b*2] + tdy*ldir[b*2+1];
    int ok = (!bad) && (md>=1.5f) && (ld<=4.5f) && (al>=0.0f);
    int oi = b*64+c;
    o_mind[oi]=md; o_laned[oi]=ld; o_align[oi]=al;
    o_cost[oi] = fmaxf(1.5f-md,0.0f) + 0.1f*ld + 0.5f*fmaxf(1.0f-al,0.0f);
    valid[oi] = ok ? 1.0f : 0.0f;
  }
}

__global__ void __launch_bounds__(64) k_select(
    const float* __restrict__ logits, const float* __restrict__ valid,
    const float* __restrict__ o_traj,
    float* __restrict__ o_scores,
    float* __restrict__ o_selidx, float* __restrict__ o_seltraj){
  int b = blockIdx.x; int t = threadIdx.x;
  float lg = logits[b*64+t];
  float mx = lg;
#pragma unroll
  for(int o=32;o;o>>=1) mx = fmaxf(mx, __shfl_xor(mx,o,64));
  float e = expf(lg-mx);
  float sm = e;
#pragma unroll
  for(int o=32;o;o>>=1) sm += __shfl_xor(sm,o,64);
  float sc = e/sm;
  o_scores[b*64+t] = sc;
  bool v = valid[b*64+t] > 0.5f;
  unsigned long long bal = __ballot(v);
  float sv = v ? sc : -1.0f;
  float v1=sv; int i1=t;
  float v2=sc; int i2=t;
#pragma unroll
  for(int o=32;o;o>>=1){
    float ov=__shfl_down(v1,o,64); int oi=__shfl_down(i1,o,64);
    if(ov>v1 || (ov==v1 && oi<i1)){ v1=ov; i1=oi; }
    ov=__shfl_down(v2,o,64); oi=__shfl_down(i2,o,64);
    if(ov>v2 || (ov==v2 && oi<i2)){ v2=ov; i2=oi; }
  }
  int sel = (bal!=0ULL) ? i1 : i2;
  sel = __shfl(sel, 0, 64);
  if(t==0) o_selidx[b] = (float)sel;
  if(t<60) o_seltraj[b*60+t] = o_traj[(size_t)(b*64+sel)*60 + t];
}

// ---------- host launch ----------
extern "C" void kernel_launch(void* const* d_in, const int* in_sizes, int n_in,
                              void* d_out, int out_size, void* d_ws, size_t ws_size,
                              hipStream_t stream) {
  const float* ego        = (const float*)d_in[0];
  const float* agents     = (const float*)d_in[1];
  const float* mp         = (const float*)d_in[2];
  const float* enc_ego_w  = (const float*)d_in[3];
  const float* enc_ego_b  = (const float*)d_in[4];
  const float* enc_ag_w   = (const float*)d_in[5];
  const float* enc_ag_b   = (const float*)d_in[6];
  const float* enc_map_w  = (const float*)d_in[7];
  const float* enc_map_b  = (const float*)d_in[8];
  const float* enc_ln_g   = (const float*)d_in[9];
  const float* enc_ln_b   = (const float*)d_in[10];
  const float* attn_in_w  = (const float*)d_in[11];
  const float* attn_in_b  = (const float*)d_in[12];
  const float* attn_out_w = (const float*)d_in[13];
  const float* attn_out_b = (const float*)d_in[14];
  const float* mlp_w1     = (const float*)d_in[15];
  const float* mlp_b1     = (const float*)d_in[16];
  const float* mlp_w2     = (const float*)d_in[17];
  const float* mlp_b2     = (const float*)d_in[18];
  const float* pl_ln_g    = (const float*)d_in[19];
  const float* pl_ln_b    = (const float*)d_in[20];
  const float* traj_w     = (const float*)d_in[21];
  const float* traj_b     = (const float*)d_in[22];
  const float* score_w    = (const float*)d_in[23];
  const float* score_b    = (const float*)d_in[24];

  float* out = (float*)d_out;
  float* o_traj    = out;            // 30720
  float* o_logits  = out + 30720;    // 512
  float* o_scores  = out + 31232;    // 512
  float* o_selidx  = out + 31744;    // 8
  float* o_seltraj = out + 31752;    // 480
  float* o_mind    = out + 32232;    // 512
  float* o_laned   = out + 32744;    // 512
  float* o_align   = out + 33256;    // 512
  float* o_cost    = out + 33768;    // 512

  float* ws = (float*)d_ws;
  float* tokens = ws;                  // 657408
  float* K      = ws + 657408;
  float* V      = ws + 1314816;
  float* wqT    = ws + 1972224;
  float* wkT    = ws + 2037760;
  float* wvT    = ws + 2103296;
  float* aowT   = ws + 2168832;
  float* fusedv = ws + 2234368;
  float* yv     = ws + 2236416;
  float* h1v    = ws + 2238464;
  float* attv   = ws + 2242560;
  float* ldir   = ws + 2244608;
  float* validv = ws + 2244624;
  unsigned* bar = (unsigned*)(ws + 2245136);   // 48 counters

  hipMemsetAsync(bar, 0, 48*sizeof(unsigned), stream);

  Params P;
  P.ego=ego; P.agents=agents; P.mp=mp;
  P.w_ego=enc_ego_w; P.b_ego=enc_ego_b; P.w_ag=enc_ag_w; P.b_ag=enc_ag_b;
  P.w_map=enc_map_w; P.b_map=enc_map_b; P.ln_g=enc_ln_g; P.ln_b=enc_ln_b;
  P.attn_in_w=attn_in_w; P.attn_in_b=attn_in_b;
  P.attn_out_w=attn_out_w; P.attn_out_b=attn_out_b;
  P.mlp_w1=mlp_w1; P.mlp_b1=mlp_b1; P.mlp_w2=mlp_w2; P.mlp_b2=mlp_b2;
  P.pl_g=pl_ln_g; P.pl_b=pl_ln_b;
  P.traj_w=traj_w; P.traj_b=traj_b; P.score_w=score_w; P.score_b=score_b;
  P.tokens=tokens; P.K=K; P.V=V; P.wqT=wqT; P.wkT=wkT; P.wvT=wvT; P.aowT=aowT;
  P.fusedv=fusedv; P.yv=yv; P.h1v=h1v; P.attv=attv; P.ldir=ldir; P.validv=validv;
  P.o_traj=o_traj; P.o_logits=o_logits; P.o_scores=o_scores;
  P.o_selidx=o_selidx; P.o_seltraj=o_seltraj;
  P.o_mind=o_mind; P.o_laned=o_laned; P.o_align=o_align; P.o_cost=o_cost;
  P.bar=bar;

  int maxb = 0;
  if(hipOccupancyMaxActiveBlocksPerMultiprocessor(&maxb, (const void*)mega, 256, 0) != hipSuccess || maxb < 1)
    maxb = 1;
  int nb = maxb * 256;
  if(nb > 512) nb = 512;

  void* kargs[] = { (void*)&P };
  hipError_t lerr = hipLaunchCooperativeKernel((const void*)mega, dim3(nb), dim3(256),
                                               kargs, 0, stream);
  if(lerr != hipSuccess){
    // Fallback: proven multi-kernel pipeline.
    k_prep_encode<<<NTOK+64+8,256,0,stream>>>(ego, agents, mp,
        enc_ego_w, enc_ego_b, enc_ag_w, enc_ag_b, enc_map_w, enc_map_b,
        enc_ln_g, enc_ln_b, attn_in_w, attn_out_w,
        tokens, wqT, wkT, wvT, aowT, ldir);
    k_kv<<<NTOK/8,256,0,stream>>>(tokens, wkT, wvT, attn_in_b, K, V);
    for(int i=0;i<NL_;i++){
      k_attn_mlp1<<<B_*NH_,256,0,stream>>>(tokens, yv, K, V, wqT, attn_in_b,
          mlp_w1, mlp_b1, pl_ln_g, pl_ln_b, fusedv, h1v, attv, i);
      k_out_mlp2<<<B_*16,256,0,stream>>>(attv, h1v, fusedv, aowT, attn_out_b,
          mlp_w2, mlp_b2, yv, i);
    }
    k_decode_constraints<<<B_*C_,256,0,stream>>>(yv, pl_ln_g, pl_ln_b,
        traj_w, traj_b, score_w, score_b, ego, agents, mp, ldir,
        o_traj, o_logits, o_mind, o_laned, o_align, o_cost, validv);
    k_select<<<B_,64,0,stream>>>(o_logits, validv, o_traj, o_scores, o_selidx, o_seltraj);
  }
}

// Round 6
// 319.287 us; speedup vs baseline: 1.5920x; 1.5920x over previous
//
#include <hip/hip_runtime.h>
#include <math.h>
#include <stddef.h>

// ---------- problem constants ----------
#define B_   8
#define A_   64
#define L_   256
#define P_   20
#define SD_  8
#define MF_  6
#define H_   256
#define NH_  8
#define HD_  32
#define NL_  3
#define C_   64
#define S_   30
#define N_   321          // 1 + A_ + L_
#define NTOK (B_*N_)      // 2568

__device__ inline float waveSum(float v){
#pragma unroll
  for(int o=32;o;o>>=1) v += __shfl_down(v,o,64);
  return v;
}

// 8-block (one batch) device-scope barrier. Counters zeroed by k_prep_encode.
// Proven correct in round-5 mega kernel (48 uses/call, repeated validation).
__device__ inline void batchBarrier(unsigned* cnt){
  __syncthreads();
  if(threadIdx.x==0){
    __threadfence();                    // release
    atomicAdd(cnt, 1u);
    while(atomicAdd(cnt, 0u) < 8u){}
    __threadfence();                    // acquire
  }
  __syncthreads();
}

// ---------- K1: encode tokens + transpose weights + ldir + zero barriers ----
__global__ void __launch_bounds__(256) k_prep_encode(
    const float* __restrict__ ego, const float* __restrict__ agents,
    const float* __restrict__ mp,
    const float* __restrict__ w_ego, const float* __restrict__ b_ego,
    const float* __restrict__ w_ag,  const float* __restrict__ b_ag,
    const float* __restrict__ w_map, const float* __restrict__ b_map,
    const float* __restrict__ ln_g,  const float* __restrict__ ln_b,
    const float* __restrict__ attn_in_w, const float* __restrict__ attn_out_w,
    float* __restrict__ tokens,
    float* __restrict__ wqT, float* __restrict__ wkT,
    float* __restrict__ wvT, float* __restrict__ aowT,
    float* __restrict__ ldir, unsigned* __restrict__ bar){
  int blk = blockIdx.x;
  int j = threadIdx.x;
  __shared__ float tile_s[64][65];
  __shared__ float in_s[SD_];
  __shared__ __align__(16) float arr[120];
  __shared__ float red[8];

  if(blk==0 && j<32) bar[j] = 0u;    // zero batch-barrier counters (layers run later)

  if(blk < NTOK){
    int b = blk / N_;
    int n = blk % N_;
    const float* W; const float* bias; int D;
    if(n==0){
      if(j<SD_) in_s[j] = ego[(b*10 + 9)*SD_ + j];
      W=w_ego; bias=b_ego; D=SD_;
    } else if(n<=A_){
      int a=n-1;
      if(j<SD_) in_s[j] = agents[(size_t)(b*A_+a)*SD_ + j];
      W=w_ag; bias=b_ag; D=SD_;
    } else {
      int l=n-1-A_;
      if(j<30) ((float4*)arr)[j] = ((const float4*)(mp + (size_t)(b*L_+l)*120))[j];
      __syncthreads();
      if(j<MF_){
        float s=0.f;
#pragma unroll
        for(int p=0;p<P_;p++) s += arr[p*MF_+j];
        in_s[j] = s * (1.0f/P_);
      }
      W=w_map; bias=b_map; D=MF_;
    }
    __syncthreads();
    float acc = bias[j];
    for(int d=0;d<D;d++) acc += in_s[d]*W[d*H_ + j];
    float s1=acc, s2=acc*acc;
#pragma unroll
    for(int o=32;o;o>>=1){ s1+=__shfl_down(s1,o,64); s2+=__shfl_down(s2,o,64); }
    if((j&63)==0){ red[j>>6]=s1; red[4+(j>>6)]=s2; }
    __syncthreads();
    float m = (red[0]+red[1]+red[2]+red[3]) * (1.0f/H_);
    float v = (red[4]+red[5]+red[6]+red[7]) * (1.0f/H_) - m*m;
    tokens[(size_t)blk*H_ + j] = (acc-m)*rsqrtf(v+1e-5f)*ln_g[j] + ln_b[j];
  } else if(blk < NTOK+64){
    // ---- transpose: dst[d*H+j] = src[j*H+d], 64x64 tiles via LDS ----
    int tid2 = blk - NTOK;
    int mat = tid2 >> 4;
    int tile = tid2 & 15;
    int jt = (tile>>2)*64, dt = (tile&3)*64;
    const float* src; float* dst;
    if(mat==0){ src = attn_in_w;            dst = wqT; }
    else if(mat==1){ src = attn_in_w + 256*H_; dst = wkT; }
    else if(mat==2){ src = attn_in_w + 512*H_; dst = wvT; }
    else { src = attn_out_w; dst = aowT; }
    int c = j & 63, r0 = (j>>6)*16;
#pragma unroll
    for(int r=0;r<16;r++) tile_s[r0+r][c] = src[(size_t)(jt + r0 + r)*H_ + dt + c];
    __syncthreads();
#pragma unroll
    for(int r=0;r<16;r++) dst[(size_t)(dt + r0 + r)*H_ + jt + c] = tile_s[c][r0+r];
  } else {
    // ---- ldir ----
    int b = blk - (NTOK+64);
    const float* p0 = mp + (size_t)(b*L_ + j)*120;
    float dx = p0[19*MF_+0]-p0[0];
    float dy = p0[19*MF_+1]-p0[1];
#pragma unroll
    for(int o=32;o;o>>=1){ dx+=__shfl_down(dx,o,64); dy+=__shfl_down(dy,o,64); }
    if((j&63)==0){ red[j>>6]=dx; red[4+(j>>6)]=dy; }
    __syncthreads();
    if(j==0){
      float sx = (red[0]+red[1]+red[2]+red[3])*(1.0f/L_);
      float sy = (red[4]+red[5]+red[6]+red[7])*(1.0f/L_);
      float nm = fmaxf(sqrtf(sx*sx+sy*sy), 1e-6f);
      ldir[b*2]=sx/nm; ldir[b*2+1]=sy/nm;
    }
  }
}

// ---------- K2: K/V projection, 8 tokens per block ----------
__global__ void __launch_bounds__(256) k_kv(
    const float* __restrict__ tokens,
    const float* __restrict__ wkT, const float* __restrict__ wvT,
    const float* __restrict__ attn_in_b,
    float* __restrict__ K, float* __restrict__ V){
  int base = blockIdx.x * 8;
  int j = threadIdx.x;
  __shared__ float tok_s[8][H_];
#pragma unroll
  for(int t=0;t<8;t++) tok_s[t][j] = tokens[(size_t)(base+t)*H_ + j];
  __syncthreads();
  float bk = attn_in_b[256+j], bv = attn_in_b[512+j];
  float aK[8], aV[8];
#pragma unroll
  for(int t=0;t<8;t++){ aK[t]=bk; aV[t]=bv; }
#pragma unroll 4
  for(int d=0;d<H_;d++){
    float wk = wkT[d*H_+j], wv = wvT[d*H_+j];
#pragma unroll
    for(int t=0;t<8;t++){ float x=tok_s[t][d]; aK[t]+=x*wk; aV[t]+=x*wv; }
  }
#pragma unroll
  for(int t=0;t<8;t++){
    K[(size_t)(base+t)*H_+j]=aK[t];
    V[(size_t)(base+t)*H_+j]=aV[t];
  }
}

// ---------- K3: one dispatch per layer: phaseA (attn+mlp1) -> batchBarrier
//             -> phaseB (out-proj + mlp2 + residual). 64 blocks = (h,b). ----
__global__ void __launch_bounds__(256) k_layer(
    const float* __restrict__ tokens, const float* __restrict__ y_in,
    const float* __restrict__ K, const float* __restrict__ V,
    const float* __restrict__ wqT, const float* __restrict__ attn_in_b,
    const float* __restrict__ mlp_w1, const float* __restrict__ mlp_b1,
    const float* __restrict__ aowT, const float* __restrict__ attn_out_b,
    const float* __restrict__ mlp_w2, const float* __restrict__ mlp_b2,
    const float* __restrict__ pl_g, const float* __restrict__ pl_b,
    float* __restrict__ fusedv, float* __restrict__ h1v,
    float* __restrict__ attv, float* __restrict__ y_out,
    unsigned* __restrict__ bar, int layer){
  const int b = blockIdx.x & 7, h = blockIdx.x >> 3;
  const int t = threadIdx.x;
  __shared__ __align__(16) float pool[1200];
  __shared__ float red[8];
  float* x_s   = pool;         // 256
  float* q_s   = pool + 256;   // 32
  float* att_s = pool + 288;   // 321 -> ends 609
  float* part1 = pool + 640;   // 256
  float* part2 = pool + 896;   // 256 -> 1152
  float* xa_s  = pool;         // phase-B aliases (phase-A data dead by then)
  float* xh_s  = pool + 256;   // 512
  float* partB = pool + 768;   // 32*9

  // ---- phase A: LN -> x_s ----
  if(layer==0){
    x_s[t] = tokens[((size_t)b*N_)*H_ + t];
  } else {
    float yvv = y_in[b*H_+t];
    float s1=yvv, s2=yvv*yvv;
#pragma unroll
    for(int o=32;o;o>>=1){ s1+=__shfl_down(s1,o,64); s2+=__shfl_down(s2,o,64); }
    if((t&63)==0){ red[t>>6]=s1; red[4+(t>>6)]=s2; }
    __syncthreads();
    float m = (red[0]+red[1]+red[2]+red[3])*(1.0f/H_);
    float v = (red[4]+red[5]+red[6]+red[7])*(1.0f/H_) - m*m;
    x_s[t] = (yvv-m)*rsqrtf(v+1e-5f)*pl_g[t] + pl_b[t];
  }
  __syncthreads();
  if(h==0) fusedv[b*H_+t] = x_s[t];
  // Q slice (head h, 32 cols, 8-way K-split)
  {
    int c=t&31, ks=t>>5;
    const float* w = wqT + (size_t)(ks*32)*H_ + h*HD_ + c;
    float a=0.f;
#pragma unroll 8
    for(int d=0;d<32;d++) a += x_s[ks*32+d]*w[(size_t)d*H_];
    part1[t]=a;
  }
  // MLP1 slice (64 cols, 4-way K-split)
  {
    int c2=t&63, k2=t>>6;
    const float* w1 = mlp_w1 + (size_t)layer*H_*512 + (size_t)(k2*64)*512 + h*64 + c2;
    float a=0.f;
#pragma unroll 8
    for(int d=0;d<64;d++) a += x_s[k2*64+d]*w1[(size_t)d*512];
    part2[t]=a;
  }
  __syncthreads();
  if(t<32){
    float q = attn_in_b[h*HD_+t];
#pragma unroll
    for(int ks=0;ks<8;ks++) q += part1[ks*32+t];
    q_s[t]=q;
  }
  if(t<64){
    float v = mlp_b1[layer*512 + h*64 + t];
#pragma unroll
    for(int k2=0;k2<4;k2++) v += part2[k2*64+t];
    h1v[b*512 + h*64 + t] = v*0.5f*(1.0f+erff(v*0.70710678118654752f));
  }
  __syncthreads();
  // ---- scores ----
  float4 q4[8];
  {
    const float4* qp=(const float4*)q_s;
#pragma unroll
    for(int i=0;i<8;i++) q4[i]=qp[i];
  }
  float s0;
  {
    const float4* kp=(const float4*)(K + ((size_t)(b*N_+t))*H_ + h*HD_);
    float s=0.f;
#pragma unroll
    for(int i=0;i<8;i++){ float4 kk=kp[i]; s+=kk.x*q4[i].x+kk.y*q4[i].y+kk.z*q4[i].z+kk.w*q4[i].w; }
    s0 = s*0.17677669529663687f;
  }
  float s1v = -3.0e38f;
  if(t<65){
    const float4* kp=(const float4*)(K + ((size_t)(b*N_+256+t))*H_ + h*HD_);
    float s=0.f;
#pragma unroll
    for(int i=0;i<8;i++){ float4 kk=kp[i]; s+=kk.x*q4[i].x+kk.y*q4[i].y+kk.z*q4[i].z+kk.w*q4[i].w; }
    s1v = s*0.17677669529663687f;
  }
  float mx = fmaxf(s0, s1v);
#pragma unroll
  for(int o=32;o;o>>=1) mx = fmaxf(mx, __shfl_xor(mx,o,64));
  if((t&63)==0) red[t>>6]=mx;
  __syncthreads();
  mx = fmaxf(fmaxf(red[0],red[1]),fmaxf(red[2],red[3]));
  __syncthreads();
  float p0 = expf(s0-mx);
  att_s[t]=p0;
  float lsum=p0;
  if(t<65){ float p1=expf(s1v-mx); att_s[256+t]=p1; lsum+=p1; }
#pragma unroll
  for(int o=32;o;o>>=1) lsum += __shfl_xor(lsum,o,64);
  if((t&63)==0) red[4+(t>>6)]=lsum;
  __syncthreads();
  // ---- AV ----
  {
    int o=t&31, ks=t>>5;
    int n0=ks*40, n1=(ks==7)?N_:n0+40;
    const float* Vp = V + ((size_t)(b*N_))*H_ + h*HD_ + o;
    float a=0.f;
#pragma unroll 4
    for(int n=n0;n<n1;n++) a += att_s[n]*Vp[(size_t)n*H_];
    part1[t]=a;
  }
  __syncthreads();
  if(t<32){
    float inv = 1.0f/(red[4]+red[5]+red[6]+red[7]);
    float a=0.f;
#pragma unroll
    for(int ks=0;ks<8;ks++) a += part1[ks*32+t];
    attv[b*H_ + h*HD_ + t] = a*inv;
  }
  batchBarrier(bar + layer*8 + b);
  // ---- phase B: out-proj + MLP2 + residual (32 cols/block) ----
  xa_s[t] = attv[b*H_+t];
  xh_s[t] = h1v[b*512+t];
  xh_s[256+t] = h1v[b*512+256+t];
  __syncthreads();
  {
    int c=t&31, rs=t>>5;       // 8 row-slices of 96
    int col = h*32 + c;
    float a=0.f;
    int r0=rs*96, r1=r0+96;
    int rEndA = r1<256 ? r1 : 256;
    for(int r=r0; r<rEndA; ++r) a += xa_s[r]*aowT[(size_t)r*H_+col];
    const float* w2 = mlp_w2 + (size_t)layer*512*H_;
    int rBegB = r0>256 ? r0 : 256;
    for(int r=rBegB; r<r1; ++r){ int rr=r-256; a += xh_s[rr]*w2[(size_t)rr*H_+col]; }
    partB[c*9+rs]=a;
  }
  __syncthreads();
  if(t<32){
    float s=0.f;
#pragma unroll
    for(int k=0;k<8;k++) s += partB[t*9+k];
    int colo = h*32+t;
    y_out[b*H_+colo] = s + attn_out_b[colo] + mlp_b2[layer*H_+colo] + fusedv[b*H_+colo];
  }
}

// ---------- K4: final LN + decode + constraints merged, per (b,c) ----------
__global__ void __launch_bounds__(256) k_decode_constraints(
    const float* __restrict__ y, const float* __restrict__ pl_g,
    const float* __restrict__ pl_b,
    const float* __restrict__ traj_w, const float* __restrict__ traj_b,
    const float* __restrict__ score_w, const float* __restrict__ score_b,
    const float* __restrict__ ego,
    const float* __restrict__ agents, const float* __restrict__ mp,
    const float* __restrict__ ldir,
    float* __restrict__ o_traj, float* __restrict__ o_logits,
    float* __restrict__ o_mind, float* __restrict__ o_laned,
    float* __restrict__ o_align, float* __restrict__ o_cost,
    float* __restrict__ valid){
  int b = blockIdx.x >> 6, c = blockIdx.x & 63;
  int t = threadIdx.x;
  int j = t & 63, sl = t >> 6;
  __shared__ float fs[H_];
  __shared__ float part[4][64];
  __shared__ float ds[60];
  __shared__ float ts[60];
  __shared__ float as_[A_*2];
  __shared__ float red[8];
  __shared__ float redsc[4];
  __shared__ int bad;
  float yv = y[b*H_ + t];
  float s1=yv, s2=yv*yv;
#pragma unroll
  for(int o=32;o;o>>=1){ s1+=__shfl_down(s1,o,64); s2+=__shfl_down(s2,o,64); }
  if((t&63)==0){ red[t>>6]=s1; red[4+(t>>6)]=s2; }
  if(t==0) bad=0;
  __syncthreads();
  {
    float m = (red[0]+red[1]+red[2]+red[3])*(1.0f/H_);
    float v = (red[4]+red[5]+red[6]+red[7])*(1.0f/H_) - m*m;
    fs[t] = (yv-m)*rsqrtf(v+1e-5f)*pl_g[t] + pl_b[t];
  }
  __syncthreads();
  if(j < 60){
    int col = c*60 + j;
    const float* w = traj_w + (size_t)(sl*64)*3840 + col;
    float acc=0.f;
#pragma unroll 16
    for(int d=0;d<64;d++) acc += fs[sl*64+d]*w[(size_t)d*3840];
    part[sl][j] = acc;
  }
  float lp = fs[t]*score_w[t*64 + c];
  lp = waveSum(lp);
  if((t&63)==0) redsc[t>>6]=lp;
  if(t>=128 && t<256){ int q=t-128; as_[q] = agents[(size_t)(b*A_ + (q>>1))*SD_ + (q&1)]; }
  __syncthreads();
  if(t < 60){
    float a = part[0][t]+part[1][t]+part[2][t]+part[3][t] + traj_b[c*60+t];
    ds[t] = tanhf(a)*1.5f;   // MAX_STEP
  }
  if(t==0) o_logits[b*64+c] = redsc[0]+redsc[1]+redsc[2]+redsc[3] + score_b[c];
  __syncthreads();
  if(t<2){
    float x = ego[(b*10+9)*SD_ + t];
    for(int s=0;s<S_;s++){ x += ds[s*2+t]; ts[s*2+t] = x; }
  }
  __syncthreads();
  if(t<60) o_traj[(size_t)(b*64+c)*60 + t] = ts[t];
  if(t<29){
    float dx = ts[2*t+2]-ts[2*t], dy = ts[2*t+3]-ts[2*t+1];
    if((dx*dx+dy*dy)*100.0f > 225.0f) bad=1;
  }
  if(t<28){
    float x0=ts[2*t],y0=ts[2*t+1],x1=ts[2*t+2],y1=ts[2*t+3],x2=ts[2*t+4],y2=ts[2*t+5];
    float ddx = x2-2.f*x1+x0, ddy = y2-2.f*y1+y0;
    if((ddx*ddx+ddy*ddy)*10000.0f > 25.0f) bad=1;
    float d1x=x1-x0, d1y=y1-y0;
    float cross = d1x*ddy - d1y*ddx;
    float n2 = d1x*d1x+d1y*d1y;
    float n3 = fmaxf(n2*sqrtf(n2), 1e-6f);
    if(fabsf(cross) > 0.3f*n3) bad=1;
  }
  float md2 = 3.0e38f;
  for(int idx=t; idx<S_*A_; idx+=256){
    int s = idx>>6, a = idx&63;
    float dx = ts[2*s]-as_[2*a], dy = ts[2*s+1]-as_[2*a+1];
    md2 = fminf(md2, dx*dx+dy*dy);
  }
  float lx[20], ly[20];
#pragma unroll
  for(int k=0;k<20;k++){
    int i = t + k*256;
    const float* pp = mp + (size_t)(b*5120 + i)*MF_;
    lx[k]=pp[0]; ly[k]=pp[1];
  }
  float ld2 = 3.0e38f;
  for(int s=0;s<S_;s++){
    float tx=ts[2*s], ty=ts[2*s+1];
#pragma unroll
    for(int k=0;k<20;k++){
      float dx=tx-lx[k], dy=ty-ly[k];
      ld2 = fminf(ld2, dx*dx+dy*dy);
    }
  }
  __syncthreads();
#pragma unroll
  for(int o=32;o;o>>=1) md2 = fminf(md2, __shfl_down(md2,o,64));
  if((t&63)==0) red[t>>6]=md2;
  __syncthreads();
  md2 = fminf(fminf(red[0],red[1]),fminf(red[2],red[3]));
  __syncthreads();
#pragma unroll
  for(int o=32;o;o>>=1) ld2 = fminf(ld2, __shfl_down(ld2,o,64));
  if((t&63)==0) red[t>>6]=ld2;
  __syncthreads();
  ld2 = fminf(fminf(red[0],red[1]),fminf(red[2],red[3]));
  if(t==0){
    float md = sqrtf(md2), ld = sqrtf(ld2);
    float tdx = ts[58]-ts[0], tdy = ts[59]-ts[1];
    float nm = fmaxf(sqrtf(tdx*tdx+tdy*tdy), 1e-6f);
    tdx/=nm; tdy/=nm;
    float al = tdx*ldir[b*2] + tdy*ldir[b*2+1];
    int ok = (!bad) && (md>=1.5f) && (ld<=4.5f) && (al>=0.0f);
    int oi = b*64+c;
    o_mind[oi]=md; o_laned[oi]=ld; o_align[oi]=al;
    o_cost[oi] = fmaxf(1.5f-md,0.0f) + 0.1f*ld + 0.5f*fmaxf(1.0f-al,0.0f);
    valid[oi] = ok ? 1.0f : 0.0f;
  }
}

// ---------- K5: score softmax + selection ----------
__global__ void __launch_bounds__(64) k_select(
    const float* __restrict__ logits, const float* __restrict__ valid,
    const float* __restrict__ o_traj,
    float* __restrict__ o_scores,
    float* __restrict__ o_selidx, float* __restrict__ o_seltraj){
  int b = blockIdx.x; int t = threadIdx.x;
  float lg = logits[b*64+t];
  float mx = lg;
#pragma unroll
  for(int o=32;o;o>>=1) mx = fmaxf(mx, __shfl_xor(mx,o,64));
  float e = expf(lg-mx);
  float sm = e;
#pragma unroll
  for(int o=32;o;o>>=1) sm += __shfl_xor(sm,o,64);
  float sc = e/sm;
  o_scores[b*64+t] = sc;
  bool v = valid[b*64+t] > 0.5f;
  unsigned long long bal = __ballot(v);
  float sv = v ? sc : -1.0f;
  float v1=sv; int i1=t;
  float v2=sc; int i2=t;
#pragma unroll
  for(int o=32;o;o>>=1){
    float ov=__shfl_down(v1,o,64); int oi=__shfl_down(i1,o,64);
    if(ov>v1 || (ov==v1 && oi<i1)){ v1=ov; i1=oi; }
    ov=__shfl_down(v2,o,64); oi=__shfl_down(i2,o,64);
    if(ov>v2 || (ov==v2 && oi<i2)){ v2=ov; i2=oi; }
  }
  int sel = (bal!=0ULL) ? i1 : i2;
  sel = __shfl(sel, 0, 64);
  if(t==0) o_selidx[b] = (float)sel;
  if(t<60) o_seltraj[b*60+t] = o_traj[(size_t)(b*64+sel)*60 + t];
}

// ---------- host launch ----------
extern "C" void kernel_launch(void* const* d_in, const int* in_sizes, int n_in,
                              void* d_out, int out_size, void* d_ws, size_t ws_size,
                              hipStream_t stream) {
  const float* ego        = (const float*)d_in[0];
  const float* agents     = (const float*)d_in[1];
  const float* mp         = (const float*)d_in[2];
  const float* enc_ego_w  = (const float*)d_in[3];
  const float* enc_ego_b  = (const float*)d_in[4];
  const float* enc_ag_w   = (const float*)d_in[5];
  const float* enc_ag_b   = (const float*)d_in[6];
  const float* enc_map_w  = (const float*)d_in[7];
  const float* enc_map_b  = (const float*)d_in[8];
  const float* enc_ln_g   = (const float*)d_in[9];
  const float* enc_ln_b   = (const float*)d_in[10];
  const float* attn_in_w  = (const float*)d_in[11];
  const float* attn_in_b  = (const float*)d_in[12];
  const float* attn_out_w = (const float*)d_in[13];
  const float* attn_out_b = (const float*)d_in[14];
  const float* mlp_w1     = (const float*)d_in[15];
  const float* mlp_b1     = (const float*)d_in[16];
  const float* mlp_w2     = (const float*)d_in[17];
  const float* mlp_b2     = (const float*)d_in[18];
  const float* pl_ln_g    = (const float*)d_in[19];
  const float* pl_ln_b    = (const float*)d_in[20];
  const float* traj_w     = (const float*)d_in[21];
  const float* traj_b     = (const float*)d_in[22];
  const float* score_w    = (const float*)d_in[23];
  const float* score_b    = (const float*)d_in[24];

  float* out = (float*)d_out;
  float* o_traj    = out;            // 30720
  float* o_logits  = out + 30720;    // 512
  float* o_scores  = out + 31232;    // 512
  float* o_selidx  = out + 31744;    // 8
  float* o_seltraj = out + 31752;    // 480
  float* o_mind    = out + 32232;    // 512
  float* o_laned   = out + 32744;    // 512
  float* o_align   = out + 33256;    // 512
  float* o_cost    = out + 33768;    // 512

  float* ws = (float*)d_ws;
  float* tokens = ws;                  // 657408
  float* K      = ws + 657408;
  float* V      = ws + 1314816;
  float* wqT    = ws + 1972224;
  float* wkT    = ws + 2037760;
  float* wvT    = ws + 2103296;
  float* aowT   = ws + 2168832;
  float* fusedv = ws + 2234368;
  float* yv     = ws + 2236416;
  float* h1v    = ws + 2238464;
  float* attv   = ws + 2242560;
  float* ldir   = ws + 2244608;
  float* validv = ws + 2244624;
  unsigned* bar = (unsigned*)(ws + 2245136);   // 32 counters (zeroed in prep)

  k_prep_encode<<<NTOK+64+8,256,0,stream>>>(ego, agents, mp,
      enc_ego_w, enc_ego_b, enc_ag_w, enc_ag_b, enc_map_w, enc_map_b,
      enc_ln_g, enc_ln_b, attn_in_w, attn_out_w,
      tokens, wqT, wkT, wvT, aowT, ldir, bar);
  k_kv<<<NTOK/8,256,0,stream>>>(tokens, wkT, wvT, attn_in_b, K, V);
  for(int i=0;i<NL_;i++){
    k_layer<<<B_*NH_,256,0,stream>>>(tokens, yv, K, V, wqT, attn_in_b,
        mlp_w1, mlp_b1, aowT, attn_out_b, mlp_w2, mlp_b2,
        pl_ln_g, pl_ln_b, fusedv, h1v, attv, yv, bar, i);
  }
  k_decode_constraints<<<B_*C_,256,0,stream>>>(yv, pl_ln_g, pl_ln_b,
      traj_w, traj_b, score_w, score_b, ego, agents, mp, ldir,
      o_traj, o_logits, o_mind, o_laned, o_align, o_cost, validv);
  k_select<<<B_,64,0,stream>>>(o_logits, validv, o_traj, o_scores, o_selidx, o_seltraj);
}

// Round 8
// 196.572 us; speedup vs baseline: 2.5859x; 1.6243x over previous
//
#include <hip/hip_runtime.h>
#include <math.h>
#include <stddef.h>

// ---------- problem constants ----------
#define B_   8
#define A_   64
#define L_   256
#define P_   20
#define SD_  8
#define MF_  6
#define H_   256
#define NH_  8
#define HD_  32
#define NL_  3
#define C_   64
#define S_   30
#define N_   321          // 1 + A_ + L_
#define NTOK (B_*N_)      // 2568

__device__ inline float waveSum(float v){
#pragma unroll
  for(int o=32;o;o>>=1) v += __shfl_down(v,o,64);
  return v;
}

// ---------- K1: encode tokens + transpose weights + ldir ----------
__global__ void __launch_bounds__(256) k_prep_encode(
    const float* __restrict__ ego, const float* __restrict__ agents,
    const float* __restrict__ mp,
    const float* __restrict__ w_ego, const float* __restrict__ b_ego,
    const float* __restrict__ w_ag,  const float* __restrict__ b_ag,
    const float* __restrict__ w_map, const float* __restrict__ b_map,
    const float* __restrict__ ln_g,  const float* __restrict__ ln_b,
    const float* __restrict__ attn_in_w, const float* __restrict__ attn_out_w,
    float* __restrict__ tokens,
    float* __restrict__ wqT, float* __restrict__ wkT,
    float* __restrict__ wvT, float* __restrict__ aowT,
    float* __restrict__ ldir){
  int blk = blockIdx.x;
  int j = threadIdx.x;
  __shared__ float tile_s[64][65];
  __shared__ float in_s[SD_];
  __shared__ __align__(16) float arr[120];
  __shared__ float red[8];

  if(blk < NTOK){
    int b = blk / N_;
    int n = blk % N_;
    const float* W; const float* bias; int D;
    if(n==0){
      if(j<SD_) in_s[j] = ego[(b*10 + 9)*SD_ + j];
      W=w_ego; bias=b_ego; D=SD_;
    } else if(n<=A_){
      int a=n-1;
      if(j<SD_) in_s[j] = agents[(size_t)(b*A_+a)*SD_ + j];
      W=w_ag; bias=b_ag; D=SD_;
    } else {
      int l=n-1-A_;
      if(j<30) ((float4*)arr)[j] = ((const float4*)(mp + (size_t)(b*L_+l)*120))[j];
      __syncthreads();
      if(j<MF_){
        float s=0.f;
#pragma unroll
        for(int p=0;p<P_;p++) s += arr[p*MF_+j];
        in_s[j] = s * (1.0f/P_);
      }
      W=w_map; bias=b_map; D=MF_;
    }
    __syncthreads();
    float acc = bias[j];
    for(int d=0;d<D;d++) acc += in_s[d]*W[d*H_ + j];
    float s1=acc, s2=acc*acc;
#pragma unroll
    for(int o=32;o;o>>=1){ s1+=__shfl_down(s1,o,64); s2+=__shfl_down(s2,o,64); }
    if((j&63)==0){ red[j>>6]=s1; red[4+(j>>6)]=s2; }
    __syncthreads();
    float m = (red[0]+red[1]+red[2]+red[3]) * (1.0f/H_);
    float v = (red[4]+red[5]+red[6]+red[7]) * (1.0f/H_) - m*m;
    tokens[(size_t)blk*H_ + j] = (acc-m)*rsqrtf(v+1e-5f)*ln_g[j] + ln_b[j];
  } else if(blk < NTOK+64){
    // ---- transpose: dst[d*H+j] = src[j*H+d], 64x64 tiles via LDS ----
    int tid2 = blk - NTOK;
    int mat = tid2 >> 4;
    int tile = tid2 & 15;
    int jt = (tile>>2)*64, dt = (tile&3)*64;
    const float* src; float* dst;
    if(mat==0){ src = attn_in_w;            dst = wqT; }
    else if(mat==1){ src = attn_in_w + 256*H_; dst = wkT; }
    else if(mat==2){ src = attn_in_w + 512*H_; dst = wvT; }
    else { src = attn_out_w; dst = aowT; }
    int c = j & 63, r0 = (j>>6)*16;
#pragma unroll
    for(int r=0;r<16;r++) tile_s[r0+r][c] = src[(size_t)(jt + r0 + r)*H_ + dt + c];
    __syncthreads();
#pragma unroll
    for(int r=0;r<16;r++) dst[(size_t)(dt + r0 + r)*H_ + jt + c] = tile_s[c][r0+r];
  } else {
    // ---- ldir ----
    int b = blk - (NTOK+64);
    const float* p0 = mp + (size_t)(b*L_ + j)*120;
    float dx = p0[19*MF_+0]-p0[0];
    float dy = p0[19*MF_+1]-p0[1];
#pragma unroll
    for(int o=32;o;o>>=1){ dx+=__shfl_down(dx,o,64); dy+=__shfl_down(dy,o,64); }
    if((j&63)==0){ red[j>>6]=dx; red[4+(j>>6)]=dy; }
    __syncthreads();
    if(j==0){
      float sx = (red[0]+red[1]+red[2]+red[3])*(1.0f/L_);
      float sy = (red[4]+red[5]+red[6]+red[7])*(1.0f/L_);
      float nm = fmaxf(sqrtf(sx*sx+sy*sy), 1e-6f);
      ldir[b*2]=sx/nm; ldir[b*2+1]=sy/nm;
    }
  }
}

// ---------- K2: K/V projection, 8 tokens per block ----------
__global__ void __launch_bounds__(256) k_kv(
    const float* __restrict__ tokens,
    const float* __restrict__ wkT, const float* __restrict__ wvT,
    const float* __restrict__ attn_in_b,
    float* __restrict__ K, float* __restrict__ V){
  int base = blockIdx.x * 8;
  int j = threadIdx.x;
  __shared__ float tok_s[8][H_];
#pragma unroll
  for(int t=0;t<8;t++) tok_s[t][j] = tokens[(size_t)(base+t)*H_ + j];
  __syncthreads();
  float bk = attn_in_b[256+j], bv = attn_in_b[512+j];
  float aK[8], aV[8];
#pragma unroll
  for(int t=0;t<8;t++){ aK[t]=bk; aV[t]=bv; }
#pragma unroll 4
  for(int d=0;d<H_;d++){
    float wk = wkT[d*H_+j], wv = wvT[d*H_+j];
#pragma unroll
    for(int t=0;t<8;t++){ float x=tok_s[t][d]; aK[t]+=x*wk; aV[t]+=x*wv; }
  }
#pragma unroll
  for(int t=0;t<8;t++){
    K[(size_t)(base+t)*H_+j]=aK[t];
    V[(size_t)(base+t)*H_+j]=aV[t];
  }
}

// ---------- K3a: per (batch,head): LN + Q-slice + MLP1-slice + attention ----
// 512 threads: short load chains (16/32/1-key/20), 8 waves per block.
__global__ void __launch_bounds__(512) k_attn_mlp1(
    const float* __restrict__ tokens, const float* __restrict__ y_in,
    const float* __restrict__ K, const float* __restrict__ V,
    const float* __restrict__ wqT, const float* __restrict__ attn_in_b,
    const float* __restrict__ mlp_w1, const float* __restrict__ mlp_b1,
    const float* __restrict__ pl_g, const float* __restrict__ pl_b,
    float* __restrict__ fusedv, float* __restrict__ h1v,
    float* __restrict__ attv, int layer){
  const int b = blockIdx.x & 7, h = blockIdx.x >> 3;
  const int t = threadIdx.x;
  __shared__ __align__(16) float x_s[H_];
  __shared__ __align__(16) float q_s[HD_];
  __shared__ float att_s[N_+7];
  __shared__ float part1[512];
  __shared__ float part2[512];
  __shared__ float redA[8], redB[8];

  // ---- LN -> x_s (threads 0..255) ----
  float yv = 0.f;
  if(t < H_){
    if(layer==0){
      x_s[t] = tokens[((size_t)b*N_)*H_ + t];
    } else {
      yv = y_in[b*H_ + t];
      float s1=yv, s2=yv*yv;
#pragma unroll
      for(int o=32;o;o>>=1){ s1+=__shfl_down(s1,o,64); s2+=__shfl_down(s2,o,64); }
      if((t&63)==0){ redA[t>>6]=s1; redB[t>>6]=s2; }
    }
  }
  __syncthreads();
  if(layer!=0 && t < H_){
    float m = (redA[0]+redA[1]+redA[2]+redA[3])*(1.0f/H_);
    float v = (redB[0]+redB[1]+redB[2]+redB[3])*(1.0f/H_) - m*m;
    x_s[t] = (yv-m)*rsqrtf(v+1e-5f)*pl_g[t] + pl_b[t];
  }
  __syncthreads();
  if(h==0 && t < H_) fusedv[b*H_+t] = x_s[t];

  // ---- Q slice: 32 cols x 16 K-slices of 16 rows ----
  {
    int c=t&31, ks=t>>5;
    const float* w = wqT + (size_t)(ks*16)*H_ + h*HD_ + c;
    float a=0.f;
#pragma unroll
    for(int d=0;d<16;d++) a += x_s[ks*16+d]*w[(size_t)d*H_];
    part1[t]=a;
  }
  // ---- MLP1 slice: 64 cols x 8 K-slices of 32 rows ----
  {
    int c2=t&63, k2=t>>6;
    const float* w1 = mlp_w1 + (size_t)layer*H_*512 + (size_t)(k2*32)*512 + h*64 + c2;
    float a=0.f;
#pragma unroll
    for(int d=0;d<32;d++) a += x_s[k2*32+d]*w1[(size_t)d*512];
    part2[t]=a;
  }
  __syncthreads();
  if(t<32){
    float q = attn_in_b[h*HD_+t];
#pragma unroll
    for(int ks=0;ks<16;ks++) q += part1[ks*32+t];
    q_s[t]=q;
  }
  if(t<64){
    float v = mlp_b1[layer*512 + h*64 + t];
#pragma unroll
    for(int k2=0;k2<8;k2++) v += part2[k2*64+t];
    h1v[b*512 + h*64 + t] = v*0.5f*(1.0f+erff(v*0.70710678118654752f));
  }
  __syncthreads();

  // ---- scores: one key per thread (t < 321) ----
  float s0 = -3.0e38f;
  if(t < N_){
    const float4* kp=(const float4*)(K + ((size_t)(b*N_+t))*H_ + h*HD_);
    const float4* qp=(const float4*)q_s;
    float s=0.f;
#pragma unroll
    for(int i=0;i<8;i++){ float4 kk=kp[i], qq=qp[i]; s+=kk.x*qq.x+kk.y*qq.y+kk.z*qq.z+kk.w*qq.w; }
    s0 = s*0.17677669529663687f;
  }
  float mx = s0;
#pragma unroll
  for(int o=32;o;o>>=1) mx = fmaxf(mx, __shfl_xor(mx,o,64));
  if((t&63)==0) redA[t>>6]=mx;
  __syncthreads();
  mx = fmaxf(fmaxf(fmaxf(redA[0],redA[1]),fmaxf(redA[2],redA[3])),
             fmaxf(fmaxf(redA[4],redA[5]),fmaxf(redA[6],redA[7])));
  float p0 = 0.f;
  if(t < N_){ p0 = expf(s0-mx); att_s[t]=p0; }
  float lsum = p0;
#pragma unroll
  for(int o=32;o;o>>=1) lsum += __shfl_xor(lsum,o,64);
  if((t&63)==0) redB[t>>6]=lsum;
  __syncthreads();

  // ---- AV: 32 cols x 16 n-slices of ~20 keys ----
  {
    int o=t&31, ks=t>>5;
    int n0=ks*20, n1=(ks==15)?N_:n0+20;
    const float* Vp = V + ((size_t)(b*N_))*H_ + h*HD_ + o;
    float a=0.f;
#pragma unroll 5
    for(int n=n0;n<n1;n++) a += att_s[n]*Vp[(size_t)n*H_];
    part1[t]=a;
  }
  __syncthreads();
  if(t<32){
    float inv = 1.0f/(redB[0]+redB[1]+redB[2]+redB[3]+redB[4]+redB[5]+redB[6]+redB[7]);
    float a=0.f;
#pragma unroll
    for(int ks=0;ks<16;ks++) a += part1[ks*32+t];
    attv[b*H_ + h*HD_ + t] = a*inv;
  }
}

// ---------- K3b: out-proj + MLP2 + residual -> y ----------
// 128 blocks (8b x 16 col-groups of 16), 512 threads: 32 row-slices of 24.
__global__ void __launch_bounds__(512) k_out_mlp2(
    const float* __restrict__ attv, const float* __restrict__ h1v,
    const float* __restrict__ fusedv,
    const float* __restrict__ aowT, const float* __restrict__ attn_out_b,
    const float* __restrict__ mlp_w2, const float* __restrict__ mlp_b2,
    float* __restrict__ y, int layer){
  int b  = blockIdx.x >> 4;
  int cg = blockIdx.x & 15;
  int t = threadIdx.x;
  int c = t & 15, rs = t >> 4;           // 32 row-slices of 24
  int col = cg*16 + c;
  __shared__ float xa_s[H_];
  __shared__ float xh_s[512];
  __shared__ float part[16][33];         // [c][rs]
  if(t < H_) xa_s[t] = attv[b*H_ + t];
  xh_s[t] = h1v[b*512 + t];
  __syncthreads();
  float acc = 0.f;
  int r0 = rs*24, r1 = r0+24;
  int rEndA = r1 < 256 ? r1 : 256;
#pragma unroll 8
  for(int r=r0; r<rEndA; ++r) acc += xa_s[r]*aowT[(size_t)r*H_ + col];
  const float* w2 = mlp_w2 + (size_t)layer*512*H_;
  int rBegB = r0 > 256 ? r0 : 256;
#pragma unroll 8
  for(int r=rBegB; r<r1; ++r){
    int rr = r-256;
    acc += xh_s[rr]*w2[(size_t)rr*H_ + col];
  }
  part[c][rs] = acc;
  __syncthreads();
  if(t < 16){
    int colo = cg*16 + t;
    float s = 0.f;
#pragma unroll
    for(int k=0;k<32;k++) s += part[t][k];
    y[b*H_ + colo] = s + attn_out_b[colo] + mlp_b2[layer*H_ + colo] + fusedv[b*H_ + colo];
  }
}

// ---------- K4: final LN + decode + constraints merged, per (b,c) ----------
__global__ void __launch_bounds__(256) k_decode_constraints(
    const float* __restrict__ y, const float* __restrict__ pl_g,
    const float* __restrict__ pl_b,
    const float* __restrict__ traj_w, const float* __restrict__ traj_b,
    const float* __restrict__ score_w, const float* __restrict__ score_b,
    const float* __restrict__ ego,
    const float* __restrict__ agents, const float* __restrict__ mp,
    const float* __restrict__ ldir,
    float* __restrict__ o_traj, float* __restrict__ o_logits,
    float* __restrict__ o_mind, float* __restrict__ o_laned,
    float* __restrict__ o_align, float* __restrict__ o_cost,
    float* __restrict__ valid){
  int b = blockIdx.x >> 6, c = blockIdx.x & 63;
  int t = threadIdx.x;
  int j = t & 63, sl = t >> 6;
  __shared__ float fs[H_];
  __shared__ float part[4][64];
  __shared__ float ds[60];
  __shared__ float ts[60];
  __shared__ float as_[A_*2];
  __shared__ float red[8];
  __shared__ float redsc[4];
  __shared__ int bad;
  float yv = y[b*H_ + t];
  float s1=yv, s2=yv*yv;
#pragma unroll
  for(int o=32;o;o>>=1){ s1+=__shfl_down(s1,o,64); s2+=__shfl_down(s2,o,64); }
  if((t&63)==0){ red[t>>6]=s1; red[4+(t>>6)]=s2; }
  if(t==0) bad=0;
  __syncthreads();
  {
    float m = (red[0]+red[1]+red[2]+red[3])*(1.0f/H_);
    float v = (red[4]+red[5]+red[6]+red[7])*(1.0f/H_) - m*m;
    fs[t] = (yv-m)*rsqrtf(v+1e-5f)*pl_g[t] + pl_b[t];
  }
  __syncthreads();
  if(j < 60){
    int col = c*60 + j;
    const float* w = traj_w + (size_t)(sl*64)*3840 + col;
    float acc=0.f;
#pragma unroll 16
    for(int d=0;d<64;d++) acc += fs[sl*64+d]*w[(size_t)d*3840];
    part[sl][j] = acc;
  }
  float lp = fs[t]*score_w[t*64 + c];
  lp = waveSum(lp);
  if((t&63)==0) redsc[t>>6]=lp;
  if(t>=128 && t<256){ int q=t-128; as_[q] = agents[(size_t)(b*A_ + (q>>1))*SD_ + (q&1)]; }
  __syncthreads();
  if(t < 60){
    float a = part[0][t]+part[1][t]+part[2][t]+part[3][t] + traj_b[c*60+t];
    ds[t] = tanhf(a)*1.5f;   // MAX_STEP
  }
  if(t==0) o_logits[b*64+c] = redsc[0]+redsc[1]+redsc[2]+redsc[3] + score_b[c];
  __syncthreads();
  if(t<2){
    float x = ego[(b*10+9)*SD_ + t];
    for(int s=0;s<S_;s++){ x += ds[s*2+t]; ts[s*2+t] = x; }
  }
  __syncthreads();
  if(t<60) o_traj[(size_t)(b*64+c)*60 + t] = ts[t];
  if(t<29){
    float dx = ts[2*t+2]-ts[2*t], dy = ts[2*t+3]-ts[2*t+1];
    if((dx*dx+dy*dy)*100.0f > 225.0f) bad=1;
  }
  if(t<28){
    float x0=ts[2*t],y0=ts[2*t+1],x1=ts[2*t+2],y1=ts[2*t+3],x2=ts[2*t+4],y2=ts[2*t+5];
    float ddx = x2-2.f*x1+x0, ddy = y2-2.f*y1+y0;
    if((ddx*ddx+ddy*ddy)*10000.0f > 25.0f) bad=1;
    float d1x=x1-x0, d1y=y1-y0;
    float cross = d1x*ddy - d1y*ddx;
    float n2 = d1x*d1x+d1y*d1y;
    float n3 = fmaxf(n2*sqrtf(n2), 1e-6f);
    if(fabsf(cross) > 0.3f*n3) bad=1;
  }
  float md2 = 3.0e38f;
  for(int idx=t; idx<S_*A_; idx+=256){
    int s = idx>>6, a = idx&63;
    float dx = ts[2*s]-as_[2*a], dy = ts[2*s+1]-as_[2*a+1];
    md2 = fminf(md2, dx*dx+dy*dy);
  }
  float lx[20], ly[20];
#pragma unroll
  for(int k=0;k<20;k++){
    int i = t + k*256;
    const float* pp = mp + (size_t)(b*5120 + i)*MF_;
    lx[k]=pp[0]; ly[k]=pp[1];
  }
  float ld2 = 3.0e38f;
  for(int s=0;s<S_;s++){
    float tx=ts[2*s], ty=ts[2*s+1];
#pragma unroll
    for(int k=0;k<20;k++){
      float dx=tx-lx[k], dy=ty-ly[k];
      ld2 = fminf(ld2, dx*dx+dy*dy);
    }
  }
  __syncthreads();
#pragma unroll
  for(int o=32;o;o>>=1) md2 = fminf(md2, __shfl_down(md2,o,64));
  if((t&63)==0) red[t>>6]=md2;
  __syncthreads();
  md2 = fminf(fminf(red[0],red[1]),fminf(red[2],red[3]));
  __syncthreads();
#pragma unroll
  for(int o=32;o;o>>=1) ld2 = fminf(ld2, __shfl_down(ld2,o,64));
  if((t&63)==0) red[t>>6]=ld2;
  __syncthreads();
  ld2 = fminf(fminf(red[0],red[1]),fminf(red[2],red[3]));
  if(t==0){
    float md = sqrtf(md2), ld = sqrtf(ld2);
    float tdx = ts[58]-ts[0], tdy = ts[59]-ts[1];
    float nm = fmaxf(sqrtf(tdx*tdx+tdy*tdy), 1e-6f);
    tdx/=nm; tdy/=nm;
    float al = tdx*ldir[b*2] + tdy*ldir[b*2+1];
    int ok = (!bad) && (md>=1.5f) && (ld<=4.5f) && (al>=0.0f);
    int oi = b*64+c;
    o_mind[oi]=md; o_laned[oi]=ld; o_align[oi]=al;
    o_cost[oi] = fmaxf(1.5f-md,0.0f) + 0.1f*ld + 0.5f*fmaxf(1.0f-al,0.0f);
    valid[oi] = ok ? 1.0f : 0.0f;
  }
}

// ---------- K5: score softmax + selection ----------
__global__ void __launch_bounds__(64) k_select(
    const float* __restrict__ logits, const float* __restrict__ valid,
    const float* __restrict__ o_traj,
    float* __restrict__ o_scores,
    float* __restrict__ o_selidx, float* __restrict__ o_seltraj){
  int b = blockIdx.x; int t = threadIdx.x;
  float lg = logits[b*64+t];
  float mx = lg;
#pragma unroll
  for(int o=32;o;o>>=1) mx = fmaxf(mx, __shfl_xor(mx,o,64));
  float e = expf(lg-mx);
  float sm = e;
#pragma unroll
  for(int o=32;o;o>>=1) sm += __shfl_xor(sm,o,64);
  float sc = e/sm;
  o_scores[b*64+t] = sc;
  bool v = valid[b*64+t] > 0.5f;
  unsigned long long bal = __ballot(v);
  float sv = v ? sc : -1.0f;
  float v1=sv; int i1=t;
  float v2=sc; int i2=t;
#pragma unroll
  for(int o=32;o;o>>=1){
    float ov=__shfl_down(v1,o,64); int oi=__shfl_down(i1,o,64);
    if(ov>v1 || (ov==v1 && oi<i1)){ v1=ov; i1=oi; }
    ov=__shfl_down(v2,o,64); oi=__shfl_down(i2,o,64);
    if(ov>v2 || (ov==v2 && oi<i2)){ v2=ov; i2=oi; }
  }
  int sel = (bal!=0ULL) ? i1 : i2;
  sel = __shfl(sel, 0, 64);
  if(t==0) o_selidx[b] = (float)sel;
  if(t<60) o_seltraj[b*60+t] = o_traj[(size_t)(b*64+sel)*60 + t];
}

// ---------- host launch ----------
extern "C" void kernel_launch(void* const* d_in, const int* in_sizes, int n_in,
                              void* d_out, int out_size, void* d_ws, size_t ws_size,
                              hipStream_t stream) {
  const float* ego        = (const float*)d_in[0];
  const float* agents     = (const float*)d_in[1];
  const float* mp         = (const float*)d_in[2];
  const float* enc_ego_w  = (const float*)d_in[3];
  const float* enc_ego_b  = (const float*)d_in[4];
  const float* enc_ag_w   = (const float*)d_in[5];
  const float* enc_ag_b   = (const float*)d_in[6];
  const float* enc_map_w  = (const float*)d_in[7];
  const float* enc_map_b  = (const float*)d_in[8];
  const float* enc_ln_g   = (const float*)d_in[9];
  const float* enc_ln_b   = (const float*)d_in[10];
  const float* attn_in_w  = (const float*)d_in[11];
  const float* attn_in_b  = (const float*)d_in[12];
  const float* attn_out_w = (const float*)d_in[13];
  const float* attn_out_b = (const float*)d_in[14];
  const float* mlp_w1     = (const float*)d_in[15];
  const float* mlp_b1     = (const float*)d_in[16];
  const float* mlp_w2     = (const float*)d_in[17];
  const float* mlp_b2     = (const float*)d_in[18];
  const float* pl_ln_g    = (const float*)d_in[19];
  const float* pl_ln_b    = (const float*)d_in[20];
  const float* traj_w     = (const float*)d_in[21];
  const float* traj_b     = (const float*)d_in[22];
  const float* score_w    = (const float*)d_in[23];
  const float* score_b    = (const float*)d_in[24];

  float* out = (float*)d_out;
  float* o_traj    = out;            // 30720
  float* o_logits  = out + 30720;    // 512
  float* o_scores  = out + 31232;    // 512
  float* o_selidx  = out + 31744;    // 8
  float* o_seltraj = out + 31752;    // 480
  float* o_mind    = out + 32232;    // 512
  float* o_laned   = out + 32744;    // 512
  float* o_align   = out + 33256;    // 512
  float* o_cost    = out + 33768;    // 512

  float* ws = (float*)d_ws;
  float* tokens = ws;                  // 657408
  float* K      = ws + 657408;
  float* V      = ws + 1314816;
  float* wqT    = ws + 1972224;
  float* wkT    = ws + 2037760;
  float* wvT    = ws + 2103296;
  float* aowT   = ws + 2168832;
  float* fusedv = ws + 2234368;
  float* yv     = ws + 2236416;
  float* h1v    = ws + 2238464;
  float* attv   = ws + 2242560;
  float* ldir   = ws + 2244608;
  float* validv = ws + 2244624;

  k_prep_encode<<<NTOK+64+8,256,0,stream>>>(ego, agents, mp,
      enc_ego_w, enc_ego_b, enc_ag_w, enc_ag_b, enc_map_w, enc_map_b,
      enc_ln_g, enc_ln_b, attn_in_w, attn_out_w,
      tokens, wqT, wkT, wvT, aowT, ldir);
  k_kv<<<NTOK/8,256,0,stream>>>(tokens, wkT, wvT, attn_in_b, K, V);
  for(int i=0;i<NL_;i++){
    k_attn_mlp1<<<B_*NH_,512,0,stream>>>(tokens, yv, K, V, wqT, attn_in_b,
        mlp_w1, mlp_b1, pl_ln_g, pl_ln_b, fusedv, h1v, attv, i);
    k_out_mlp2<<<B_*16,512,0,stream>>>(attv, h1v, fusedv, aowT, attn_out_b,
        mlp_w2, mlp_b2, yv, i);
  }
  k_decode_constraints<<<B_*C_,256,0,stream>>>(yv, pl_ln_g, pl_ln_b,
      traj_w, traj_b, score_w, score_b, ego, agents, mp, ldir,
      o_traj, o_logits, o_mind, o_laned, o_align, o_cost, validv);
  k_select<<<B_,64,0,stream>>>(o_logits, validv, o_traj, o_scores, o_selidx, o_seltraj);
}